// Round 7
// baseline (164.200 us; speedup 1.0000x reference)
//
#include <hip/hip_runtime.h>
#include <math.h>

// Performer FAVOR+ feature map — fused main + tiny B-prep, transposed MFMA.
//   out[t][j] = exp2( x[t].(nrm*log2e*proj[j]) + dlog[t] ) + ratio*eps
//   dlog[t] = -0.5*||x[t]||^2*log2e - 4   (ratio=2^-4 folded into exponent)
//   bf16 hi/lo 3-term MFMA (drop lo*lo; absmax 3e-8, verified R2..R6).
//
// KEY (R7): operands swapped vs R6 — A = proj (M=features), B = x (N=tokens).
// A/B frag layouts are symmetric, so frag builders are unchanged; but D now
// has col=token(li), row=feature(q*4+reg): each lane owns 4 CONSECUTIVE
// features of one token -> float4 stores, 1 KB dense per wave-instr
// (R6: 64 scalar dword stores/thread scattering 256 B/instr).
//
// Main: 512 thr = 8 waves, tile 128 tokens x 256 feats.
//   Stage: wave w cvts its 16 tokens -> hi/lo bf16 x-frags in LDS (32 KB,
//   conflict-free ds_write_b128), dlog via 2 shfl. One barrier.
//   Compute: wave w owns feat tiles {2w,2w+1} (8 proj frags = 32 VGPR, L2-hot
//   global loads); loops 8 token tiles: 4 ds_read_b128 + 12 MFMA + 8 exp2 +
//   2 dwordx4 stores.

typedef short bf16x8 __attribute__((ext_vector_type(8)));
typedef float f32x4  __attribute__((ext_vector_type(4)));

__device__ __forceinline__ unsigned short f2bf_rne(float f) {
    unsigned u = __builtin_bit_cast(unsigned, f);
    unsigned r = u + 0x7FFFu + ((u >> 16) & 1u);
    return (unsigned short)(r >> 16);
}

__device__ __forceinline__ void f2bf_hilo(float f, unsigned short& h, unsigned short& l) {
    h = f2bf_rne(f);
    float fh = __builtin_bit_cast(float, (unsigned)h << 16);
    l = f2bf_rne(f - fh);
}

// ---- prep_b: proj (256x64 fp32) -> frag-ordered bf16 hi/lo (64 KB) ----
// frag index ((nt*2 + kc)*2 + h), 64 lanes x 8 bf16. Scale = 64^-0.25 * log2(e)
// so the MFMA result is already in log2 domain.
__global__ void performer_prep_b(const float* __restrict__ proj, short* __restrict__ bfrag) {
    int g    = blockIdx.x * 256 + threadIdx.x;   // 0..4095
    int lane = g & 63;
    int h    = (g >> 6) & 1;
    int kc   = (g >> 7) & 1;
    int nt   = g >> 8;                           // 0..15
    int n    = nt * 16 + (lane & 15);
    int kb   = kc * 32 + (lane >> 4) * 8;
    const float scl = 0.51006972784f;            // 64^-0.25 * log2(e)
    float4 v0 = *(const float4*)&proj[n * 64 + kb];
    float4 v1 = *(const float4*)&proj[n * 64 + kb + 4];
    float vals[8] = {v0.x, v0.y, v0.z, v0.w, v1.x, v1.y, v1.z, v1.w};
    union { unsigned short us[8]; bf16x8 v; } o;
    #pragma unroll
    for (int j = 0; j < 8; ++j) {
        unsigned short hi, lo;
        f2bf_hilo(vals[j] * scl, hi, lo);
        o.us[j] = h ? lo : hi;
    }
    *(bf16x8*)&bfrag[g * 8] = o.v;
}

// ---- fused main ----
__global__ __launch_bounds__(512, 4)
void performer_fm_kernel(const float* __restrict__ x,
                         const short* __restrict__ bfrag,
                         float* __restrict__ out) {
    // x frags: 8 tt x 4 frags(h0,l0,h1,l1) x 64 lanes x 16 B = 32 KB
    __shared__ __align__(16) short Af[8 * 4 * 64 * 8];
    __shared__ float dlg[128];

    const int wave = threadIdx.x >> 6;
    const int lane = threadIdx.x & 63;
    const int q    = lane >> 4;
    const int li   = lane & 15;
    const long t0  = (long)blockIdx.x * 128;

    // ---- staging: wave w -> tokens [t0+16w, t0+16w+16) ----
    const float4* xr = (const float4*)(x + (t0 + wave * 16 + li) * 64);
    float4 a0 = xr[q * 2];          // k = q*8 .. q*8+3
    float4 a1 = xr[q * 2 + 1];      // k = q*8+4 .. q*8+7
    float4 a2 = xr[8 + q * 2];      // k = 32+q*8 ..
    float4 a3 = xr[8 + q * 2 + 1];

    // ---- proj fragments (L2-hot, independent of staging) ----
    bf16x8 Ph[2][2], Pl[2][2];
    {
        const bf16x8* bw = (const bf16x8*)bfrag;
        #pragma unroll
        for (int nf = 0; nf < 2; ++nf) {
            int ntg = wave * 2 + nf;
            #pragma unroll
            for (int kc = 0; kc < 2; ++kc) {
                Ph[nf][kc] = bw[((ntg * 2 + kc) * 2 + 0) * 64 + lane];
                Pl[nf][kc] = bw[((ntg * 2 + kc) * 2 + 1) * 64 + lane];
            }
        }
    }

    // exact fp32 ||x||^2 for token (16w+li): reduce across q groups
    float p = a0.x * a0.x + a0.y * a0.y + a0.z * a0.z + a0.w * a0.w
            + a1.x * a1.x + a1.y * a1.y + a1.z * a1.z + a1.w * a1.w
            + a2.x * a2.x + a2.y * a2.y + a2.z * a2.z + a2.w * a2.w
            + a3.x * a3.x + a3.y * a3.y + a3.z * a3.z + a3.w * a3.w;
    p += __shfl_xor(p, 16);
    p += __shfl_xor(p, 32);
    const float NHL2E = -0.7213475204444817f;    // -0.5*log2(e)
    if (q == 0) dlg[wave * 16 + li] = fmaf(NHL2E, p, -4.0f);

    // register hi/lo pack -> LDS frags (conflict-free b128 at base+lane*16)
    {
        float v0[8] = {a0.x, a0.y, a0.z, a0.w, a1.x, a1.y, a1.z, a1.w};
        float v1[8] = {a2.x, a2.y, a2.z, a2.w, a3.x, a3.y, a3.z, a3.w};
        union { unsigned short us[8]; bf16x8 v; } h0, l0, h1, l1;
        #pragma unroll
        for (int j = 0; j < 8; ++j) {
            f2bf_hilo(v0[j], h0.us[j], l0.us[j]);
            f2bf_hilo(v1[j], h1.us[j], l1.us[j]);
        }
        bf16x8* As = (bf16x8*)Af;
        const int base = wave * 4 * 64 + lane;   // tt = wave
        As[base]       = h0.v;
        As[base + 64]  = l0.v;
        As[base + 128] = h1.v;
        As[base + 192] = l1.v;
    }
    __syncthreads();

    const bf16x8* As = (const bf16x8*)Af;
    const float REPS = 6.25e-6f;                 // ratio*eps

    #pragma unroll 2
    for (int tt = 0; tt < 8; ++tt) {
        const int ab = tt * 256 + lane;
        bf16x8 xh0 = As[ab];
        bf16x8 xl0 = As[ab + 64];
        bf16x8 xh1 = As[ab + 128];
        bf16x8 xl1 = As[ab + 192];
        const float dl = dlg[tt * 16 + li];      // 4-way same-addr broadcast

        // lane owns token t0+tt*16+li, features (wave*2+nf)*16 + q*4 .. +3
        float* orow = out + (t0 + tt * 16 + li) * 256 + wave * 32 + q * 4;
        #pragma unroll
        for (int nf = 0; nf < 2; ++nf) {
            f32x4 acc = {0.f, 0.f, 0.f, 0.f};
            acc = __builtin_amdgcn_mfma_f32_16x16x32_bf16(Pl[nf][0], xh0, acc, 0, 0, 0);
            acc = __builtin_amdgcn_mfma_f32_16x16x32_bf16(Ph[nf][0], xl0, acc, 0, 0, 0);
            acc = __builtin_amdgcn_mfma_f32_16x16x32_bf16(Ph[nf][0], xh0, acc, 0, 0, 0);
            acc = __builtin_amdgcn_mfma_f32_16x16x32_bf16(Pl[nf][1], xh1, acc, 0, 0, 0);
            acc = __builtin_amdgcn_mfma_f32_16x16x32_bf16(Ph[nf][1], xl1, acc, 0, 0, 0);
            acc = __builtin_amdgcn_mfma_f32_16x16x32_bf16(Ph[nf][1], xh1, acc, 0, 0, 0);
            // D: col = li (token), row = q*4 + r (feature) -> float4 store
            float4 o;
            o.x = __builtin_amdgcn_exp2f(acc[0] + dl) + REPS;
            o.y = __builtin_amdgcn_exp2f(acc[1] + dl) + REPS;
            o.z = __builtin_amdgcn_exp2f(acc[2] + dl) + REPS;
            o.w = __builtin_amdgcn_exp2f(acc[3] + dl) + REPS;
            *(float4*)(orow + nf * 16) = o;
        }
    }
}

extern "C" void kernel_launch(void* const* d_in, const int* in_sizes, int n_in,
                              void* d_out, int out_size, void* d_ws, size_t ws_size,
                              hipStream_t stream) {
    const float* x    = (const float*)d_in[0];
    const float* proj = (const float*)d_in[1];
    float* out        = (float*)d_out;
    short* bfrag      = (short*)d_ws;            // 64 KB frag-ordered proj
    const int ntok    = in_sizes[0] / 64;        // 131072

    performer_prep_b<<<16, 256, 0, stream>>>(proj, bfrag);
    performer_fm_kernel<<<ntok / 128, 512, 0, stream>>>(x, bfrag, out);
}

// Round 8
// 162.233 us; speedup vs baseline: 1.0121x; 1.0121x over previous
//
#include <hip/hip_runtime.h>
#include <math.h>

// Performer FAVOR+ feature map — wave-autonomous, barrier-free, LDS-free.
//   out[t][j] = exp2( x[t].(nrm*log2e*proj[j]) + dlog[t] ) + ratio*eps
//   dlog[t] = -0.5*||x[t]||^2*log2e - 4   (ratio=2^-4 folded into exponent)
//   bf16 hi/lo 3-term MFMA (drop lo*lo; absmax 3e-8, verified R2..R7).
//
// R8: each wave owns 32 tokens x 256 feats. x-frags built once in registers
// (8 frags = 32 VGPR) from direct global loads; dl is in-lane (token==li).
// B (proj) streamed per-nf from frag-ordered ws: 4 x 16 B L2-hot loads, 16
// independent iterations -> deep pipelining, no barrier, no LDS.
// MFMA orientation: A=proj (M=feat), B=x (N=token) -> D col=token(li),
// row=feat(q*4+r) -> float4 stores.

typedef short bf16x8 __attribute__((ext_vector_type(8)));
typedef float f32x4  __attribute__((ext_vector_type(4)));

__device__ __forceinline__ unsigned short f2bf_rne(float f) {
    unsigned u = __builtin_bit_cast(unsigned, f);
    unsigned r = u + 0x7FFFu + ((u >> 16) & 1u);
    return (unsigned short)(r >> 16);
}

__device__ __forceinline__ void f2bf_hilo(float f, unsigned short& h, unsigned short& l) {
    h = f2bf_rne(f);
    float fh = __builtin_bit_cast(float, (unsigned)h << 16);
    l = f2bf_rne(f - fh);
}

// ---- prep_b: proj (256x64 fp32) -> frag-ordered bf16 hi/lo (64 KB) ----
// index ((nf*2 + kc)*2 + h)*64 + lane, 8 bf16 each. Scale = 64^-0.25 * log2(e).
__global__ void performer_prep_b(const float* __restrict__ proj, short* __restrict__ bfrag) {
    int g    = blockIdx.x * 256 + threadIdx.x;   // 0..4095
    int lane = g & 63;
    int h    = (g >> 6) & 1;
    int kc   = (g >> 7) & 1;
    int nf   = g >> 8;                           // 0..15
    int n    = nf * 16 + (lane & 15);
    int kb   = kc * 32 + (lane >> 4) * 8;
    const float scl = 0.51006972784f;            // 64^-0.25 * log2(e)
    float4 v0 = *(const float4*)&proj[n * 64 + kb];
    float4 v1 = *(const float4*)&proj[n * 64 + kb + 4];
    float vals[8] = {v0.x, v0.y, v0.z, v0.w, v1.x, v1.y, v1.z, v1.w};
    union { unsigned short us[8]; bf16x8 v; } o;
    #pragma unroll
    for (int j = 0; j < 8; ++j) {
        unsigned short hi, lo;
        f2bf_hilo(vals[j] * scl, hi, lo);
        o.us[j] = h ? lo : hi;
    }
    *(bf16x8*)&bfrag[g * 8] = o.v;
}

// convert one token-set (4 float4 of x) into 4 MFMA frags + dl
__device__ __forceinline__ void build_xfrags(const float4* xr, int q,
                                             bf16x8& xh0, bf16x8& xl0,
                                             bf16x8& xh1, bf16x8& xl1,
                                             float& dl) {
    float4 a0 = xr[q * 2];          // k = q*8 .. q*8+3
    float4 a1 = xr[q * 2 + 1];      // k = q*8+4 .. q*8+7
    float4 a2 = xr[8 + q * 2];      // k = 32+q*8 ..
    float4 a3 = xr[8 + q * 2 + 1];

    float p = a0.x * a0.x + a0.y * a0.y + a0.z * a0.z + a0.w * a0.w
            + a1.x * a1.x + a1.y * a1.y + a1.z * a1.z + a1.w * a1.w
            + a2.x * a2.x + a2.y * a2.y + a2.z * a2.z + a2.w * a2.w
            + a3.x * a3.x + a3.y * a3.y + a3.z * a3.z + a3.w * a3.w;
    p += __shfl_xor(p, 16);
    p += __shfl_xor(p, 32);         // all 4 q-lanes of token li now hold ||x||^2
    const float NHL2E = -0.7213475204444817f;    // -0.5*log2(e)
    dl = fmaf(NHL2E, p, -4.0f);

    float v0[8] = {a0.x, a0.y, a0.z, a0.w, a1.x, a1.y, a1.z, a1.w};
    float v1[8] = {a2.x, a2.y, a2.z, a2.w, a3.x, a3.y, a3.z, a3.w};
    union { unsigned short us[8]; bf16x8 v; } h0, l0, h1, l1;
    #pragma unroll
    for (int j = 0; j < 8; ++j) {
        f2bf_hilo(v0[j], h0.us[j], l0.us[j]);
        f2bf_hilo(v1[j], h1.us[j], l1.us[j]);
    }
    xh0 = h0.v; xl0 = l0.v; xh1 = h1.v; xl1 = l1.v;
}

// ---- main: 256 thr = 4 waves; wave owns 32 tokens x 256 feats ----
__global__ __launch_bounds__(256, 5)
void performer_fm_kernel(const float* __restrict__ x,
                         const short* __restrict__ bfrag,
                         float* __restrict__ out) {
    const int wave = threadIdx.x >> 6;
    const int lane = threadIdx.x & 63;
    const int q    = lane >> 4;
    const int li   = lane & 15;
    const long t0  = ((long)blockIdx.x * 4 + wave) * 32;

    // x-frags for token sets A (t0+li) and B (t0+16+li), built once
    bf16x8 ah0, al0, ah1, al1, bh0, bl0, bh1, bl1;
    float dla, dlb;
    build_xfrags((const float4*)(x + (t0 + li) * 64),      q, ah0, al0, ah1, al1, dla);
    build_xfrags((const float4*)(x + (t0 + 16 + li) * 64), q, bh0, bl0, bh1, bl1, dlb);

    const bf16x8* bw = (const bf16x8*)bfrag;
    const float REPS = 6.25e-6f;                 // ratio*eps

    float* orowA = out + (t0 + li) * 256 + q * 4;
    float* orowB = orowA + 16 * 256;

    #pragma unroll 2
    for (int nf = 0; nf < 16; ++nf) {
        // proj frags for feature tile nf (L2-hot, independent of acc chain)
        bf16x8 Ph0 = bw[(nf * 4 + 0) * 64 + lane];   // kc0 hi
        bf16x8 Pl0 = bw[(nf * 4 + 1) * 64 + lane];   // kc0 lo
        bf16x8 Ph1 = bw[(nf * 4 + 2) * 64 + lane];   // kc1 hi
        bf16x8 Pl1 = bw[(nf * 4 + 3) * 64 + lane];   // kc1 lo

        f32x4 accA = {0.f, 0.f, 0.f, 0.f};
        f32x4 accB = {0.f, 0.f, 0.f, 0.f};
        accA = __builtin_amdgcn_mfma_f32_16x16x32_bf16(Pl0, ah0, accA, 0, 0, 0);
        accB = __builtin_amdgcn_mfma_f32_16x16x32_bf16(Pl0, bh0, accB, 0, 0, 0);
        accA = __builtin_amdgcn_mfma_f32_16x16x32_bf16(Ph0, al0, accA, 0, 0, 0);
        accB = __builtin_amdgcn_mfma_f32_16x16x32_bf16(Ph0, bl0, accB, 0, 0, 0);
        accA = __builtin_amdgcn_mfma_f32_16x16x32_bf16(Ph0, ah0, accA, 0, 0, 0);
        accB = __builtin_amdgcn_mfma_f32_16x16x32_bf16(Ph0, bh0, accB, 0, 0, 0);
        accA = __builtin_amdgcn_mfma_f32_16x16x32_bf16(Pl1, ah1, accA, 0, 0, 0);
        accB = __builtin_amdgcn_mfma_f32_16x16x32_bf16(Pl1, bh1, accB, 0, 0, 0);
        accA = __builtin_amdgcn_mfma_f32_16x16x32_bf16(Ph1, al1, accA, 0, 0, 0);
        accB = __builtin_amdgcn_mfma_f32_16x16x32_bf16(Ph1, bl1, accB, 0, 0, 0);
        accA = __builtin_amdgcn_mfma_f32_16x16x32_bf16(Ph1, ah1, accA, 0, 0, 0);
        accB = __builtin_amdgcn_mfma_f32_16x16x32_bf16(Ph1, bh1, accB, 0, 0, 0);

        // D: col = li (token), row = q*4 + r (feature) -> float4 store
        float4 oA, oB;
        oA.x = __builtin_amdgcn_exp2f(accA[0] + dla) + REPS;
        oA.y = __builtin_amdgcn_exp2f(accA[1] + dla) + REPS;
        oA.z = __builtin_amdgcn_exp2f(accA[2] + dla) + REPS;
        oA.w = __builtin_amdgcn_exp2f(accA[3] + dla) + REPS;
        oB.x = __builtin_amdgcn_exp2f(accB[0] + dlb) + REPS;
        oB.y = __builtin_amdgcn_exp2f(accB[1] + dlb) + REPS;
        oB.z = __builtin_amdgcn_exp2f(accB[2] + dlb) + REPS;
        oB.w = __builtin_amdgcn_exp2f(accB[3] + dlb) + REPS;
        *(float4*)(orowA + nf * 16) = oA;
        *(float4*)(orowB + nf * 16) = oB;
    }
}

extern "C" void kernel_launch(void* const* d_in, const int* in_sizes, int n_in,
                              void* d_out, int out_size, void* d_ws, size_t ws_size,
                              hipStream_t stream) {
    const float* x    = (const float*)d_in[0];
    const float* proj = (const float*)d_in[1];
    float* out        = (float*)d_out;
    short* bfrag      = (short*)d_ws;            // 64 KB frag-ordered proj
    const int ntok    = in_sizes[0] / 64;        // 131072

    performer_prep_b<<<16, 256, 0, stream>>>(proj, bfrag);
    performer_fm_kernel<<<ntok / 128, 256, 0, stream>>>(x, bfrag, out);
}